// Round 14
// baseline (327.779 us; speedup 1.0000x reference)
//
#include <hip/hip_runtime.h>
#include <hip/hip_bf16.h>

typedef __attribute__((ext_vector_type(8))) short short8;
typedef __attribute__((ext_vector_type(4))) float f32x4;

#define L2E 1.442695041f
#define SCAN_B 256

__device__ __forceinline__ short f2bf(float f) {
  union { __hip_bfloat16 b; short s; } u;
  u.b = __float2bfloat16(f);
  return u.s;
}
__device__ __forceinline__ float b2f(short s) {
  unsigned u = ((unsigned)(unsigned short)s) << 16;
  return __uint_as_float(u);
}

// ---- f32/bf16 storage accessors ----
__device__ __forceinline__ float ldh(const float* p, size_t i) { return p[i]; }
__device__ __forceinline__ float ldh(const __hip_bfloat16* p, size_t i) {
  return __bfloat162float(p[i]);
}
__device__ __forceinline__ void sth(float* p, size_t i, float v) { p[i] = v; }
__device__ __forceinline__ void sth(__hip_bfloat16* p, size_t i, float v) {
  p[i] = __float2bfloat16(v);
}

__device__ __forceinline__ short8 load_gfrag(const float* g, size_t base) {
  const float4* gp = (const float4*)(g + base);
  float4 a = gp[0], b = gp[1];
  short8 t;
  t[0]=f2bf(a.x); t[1]=f2bf(a.y); t[2]=f2bf(a.z); t[3]=f2bf(a.w);
  t[4]=f2bf(b.x); t[5]=f2bf(b.y); t[6]=f2bf(b.z); t[7]=f2bf(b.w);
  return t;
}
__device__ __forceinline__ short8 load_gfrag(const __hip_bfloat16* g, size_t base) {
  return *(const short8*)(g + base);
}

// ---------------- weight image layout (bytes) ----------------
#define OFF_WIH0 0        // bf16 [208][32], swz (row&3)<<3, exp2-prescaled
#define OFF_WHH0 13312    // bf16 [208][64], swz (row&7)<<3, exp2-prescaled
#define OFF_WIH1 39936
#define OFF_WHH1 66560
#define OFF_B0   93184    // f32 [208], exp2-prescaled
#define OFF_B1   94016
#define OFF_FCW  94848    // f32 [64] (raw, zero-padded 50..63)
#define IMG_BYTES 95104

// ================= edge dtype autodetect (A/C paths) =================
__global__ void k_detect(const int* __restrict__ ei, int E, int* __restrict__ flag) {
  if (threadIdx.x == 0 && blockIdx.x == 0) {
    int odd_nz = 0, even_nz = 0;
    int m = min(128, E);
    for (int i = 0; i < m; ++i) {
      odd_nz |= (ei[2 * i + 1] != 0);
      even_nz |= (ei[2 * i] != 0);
    }
    *flag = (even_nz && !odd_nz) ? 1 : 0;
  }
}

// ================= GCN =================

__global__ void k_count(const int* __restrict__ ei, int E,
                        const int* __restrict__ flag, int* __restrict__ cnt) {
  int e = blockIdx.x * blockDim.x + threadIdx.x;
  if (e < E) {
    int d = (*flag) ? ei[2 * (E + e)] : ei[E + e];
    atomicAdd(&cnt[d], 1);
  }
}

// read edges once: block-local dtype detect + packed emit + count atomics
__global__ void k_convert(const int* __restrict__ ei, int E,
                          unsigned int* __restrict__ ed, int* __restrict__ cnt) {
  __shared__ int sflag;
  if (threadIdx.x == 0) {
    int odd_nz = 0, even_nz = 0;
    int m = min(128, E);
    for (int i = 0; i < m; ++i) {
      odd_nz |= (ei[2 * i + 1] != 0);
      even_nz |= (ei[2 * i] != 0);
    }
    sflag = (even_nz && !odd_nz) ? 1 : 0;
  }
  __syncthreads();
  int is64 = sflag;
  int e = blockIdx.x * blockDim.x + threadIdx.x;
  if (e < E) {
    int s = is64 ? ei[2 * e] : ei[e];
    int d = is64 ? ei[2 * (E + e)] : ei[E + e];
    ed[e] = (unsigned int)s | ((unsigned int)d << 16);
    atomicAdd(&cnt[d], 1);
  }
}

__global__ void k_dinv(const int* __restrict__ cnt, float* __restrict__ dinv, int N) {
  int i = blockIdx.x * blockDim.x + threadIdx.x;
  if (i < N) dinv[i] = rsqrtf((float)cnt[i] + 1.0f);
}

// ---- grid-parallel scan, stage A: per-block sums (+dinv emission) ----
__global__ __launch_bounds__(256) void k_scanA(const int* __restrict__ cnt,
                                               float* __restrict__ dinv,
                                               int* __restrict__ bsum, int N) {
  __shared__ int red[256];
  int b = blockIdx.x, t = threadIdx.x;
  int chunk = (N + SCAN_B - 1) / SCAN_B;
  int lo = b * chunk, hi = min(lo + chunk, N);
  int s = 0;
  for (int i = lo + t; i < hi; i += 256) {
    int c = cnt[i];
    dinv[i] = rsqrtf((float)c + 1.0f);
    s += c;
  }
  red[t] = s;
  __syncthreads();
  for (int o = 128; o > 0; o >>= 1) {
    if (t < o) red[t] += red[t + o];
    __syncthreads();
  }
  if (t == 0) bsum[b] = red[0];
}

// ---- stage B: block base from bsum-scan, then tiled in-place excl scan ----
__global__ __launch_bounds__(256) void k_scanB(int* __restrict__ a,
                                               const int* __restrict__ bsum,
                                               int N) {
  __shared__ int sh[256];
  int b = blockIdx.x, t = threadIdx.x;
  int chunk = (N + SCAN_B - 1) / SCAN_B;
  int lo = b * chunk, hi = min(lo + chunk, N);
  sh[t] = bsum[t];
  __syncthreads();
  for (int o = 1; o < 256; o <<= 1) {
    int u = (t >= o) ? sh[t - o] : 0;
    __syncthreads();
    sh[t] += u;
    __syncthreads();
  }
  int carry = (b == 0) ? 0 : sh[b - 1];
  __syncthreads();
  for (int i0 = lo; i0 < hi; i0 += 256) {
    int i = i0 + t;
    int c = (i < hi) ? a[i] : 0;
    sh[t] = c;
    __syncthreads();
    for (int o = 1; o < 256; o <<= 1) {
      int u = (t >= o) ? sh[t - o] : 0;
      __syncthreads();
      sh[t] += u;
      __syncthreads();
    }
    if (i < hi) a[i] = carry + sh[t] - c;  // exclusive
    carry += sh[255];
    __syncthreads();
  }
}

// packed fill pass: dst-range window keeps csr writes L2-coalesced
__global__ void k_fill_p(const unsigned int* __restrict__ ed, int E,
                         int* __restrict__ rowst,
                         unsigned short* __restrict__ csr, int lo, int hi) {
  int e = blockIdx.x * blockDim.x + threadIdx.x;
  if (e < E) {
    unsigned int v = ed[e];
    int d = (int)(v >> 16);
    if (d >= lo && d < hi) {
      int p = atomicAdd(&rowst[d], 1);
      csr[p] = (unsigned short)(v & 0xFFFFu);
    }
  }
}

// legacy fill (path A)
template <typename CT>
__global__ void k_fill(const int* __restrict__ ei, int E,
                       const int* __restrict__ flag,
                       int* __restrict__ rowst, CT* __restrict__ csr,
                       int lo, int hi) {
  int e = blockIdx.x * blockDim.x + threadIdx.x;
  if (e < E) {
    int is64 = *flag;
    int d = is64 ? ei[2 * (E + e)] : ei[E + e];
    if (d >= lo && d < hi) {
      int s = is64 ? ei[2 * e] : ei[e];
      int p = atomicAdd(&rowst[d], 1);
      csr[p] = (CT)s;
    }
  }
}

// hs[n][g] = (x[n] @ W)[g] * dinv[n]
template <typename HT>
__global__ __launch_bounds__(256) void k_hs(const float* __restrict__ x,
                                            const float* __restrict__ Wg,
                                            const float* __restrict__ dinv,
                                            HT* __restrict__ hs, int N) {
  __shared__ __align__(16) float xt[64][132];
  __shared__ __align__(16) float Wl[128][32];
  int tid = threadIdx.x;
  int nb = blockIdx.x * 64;
  for (int i = tid; i < 4096; i += 256) Wl[i >> 5][i & 31] = Wg[i];
  const float4* xv = (const float4*)x;
  for (int i = tid; i < 2048; i += 256) {
    int r = i >> 5, c = i & 31;
    float4 v = make_float4(0.f, 0.f, 0.f, 0.f);
    if (nb + r < N) v = xv[(size_t)(nb + r) * 32 + c];
    *(float4*)&xt[r][c * 4] = v;
  }
  __syncthreads();
  int nl = tid >> 2, gq = (tid & 3) * 8;
  float a[8];
#pragma unroll
  for (int j = 0; j < 8; ++j) a[j] = 0.f;
  for (int k = 0; k < 128; ++k) {
    float xk = xt[nl][k];
#pragma unroll
    for (int j = 0; j < 8; ++j) a[j] += xk * Wl[k][gq + j];
  }
  int n = nb + nl;
  if (n < N) {
    float d = dinv[n];
#pragma unroll
    for (int j = 0; j < 8; ++j) sth(hs, (size_t)n * 32 + gq + j, a[j] * d);
  }
}

// 4 nodes per wave; batched rowst window load + 4 prefetched idx loads
template <typename HT, typename GT, typename CT>
__global__ void k_gather4(const CT* __restrict__ csr, const int* __restrict__ rowst,
                          const HT* __restrict__ hs, const float* __restrict__ dinv,
                          const float* __restrict__ bg, GT* __restrict__ gout,
                          int N) {
  long long gtid = (long long)blockIdx.x * blockDim.x + threadIdx.x;
  int wave = (int)(gtid >> 6);
  int n0 = wave * 4;
  if (n0 >= N) return;
  int l = threadIdx.x & 63;
  int gf = l & 31, j = l >> 5;
  // lanes 0..4 hold rowst[n0-1 .. n0+3] (0 when OOB)
  int rr = 0;
  int ri = n0 - 1 + l;
  if (l <= 4 && ri >= 0 && ri < N) rr = rowst[ri];
  int st[4], en[4], idx[4], deg[4];
#pragma unroll
  for (int q = 0; q < 4; ++q) {
    st[q] = __shfl(rr, q);
    en[q] = __shfl(rr, q + 1);
    deg[q] = en[q] - st[q];
  }
#pragma unroll
  for (int q = 0; q < 4; ++q)
    idx[q] = (n0 + q < N && l < deg[q]) ? (int)csr[st[q] + l] : 0;
  float bgv = bg[gf];
#pragma unroll
  for (int q = 0; q < 4; ++q) {
    int w = n0 + q;
    if (w >= N) break;
    float acc = 0.f;
    int dm = min(deg[q], 64);
#pragma unroll 1
    for (int base = 0; base < 64; base += 16) {
      if (base >= dm) break;
#pragma unroll
      for (int i = 0; i < 8; ++i) {
        int e = base + 2 * i + j;
        int src = __shfl(idx[q], e);
        float v = ldh(hs, (size_t)src * 32 + gf);
        acc += (e < dm) ? v : 0.f;
      }
    }
    for (int k2 = st[q] + 64 + j; k2 < en[q]; k2 += 2)
      acc += ldh(hs, (size_t)csr[k2] * 32 + gf);
    acc += __shfl_xor(acc, 32);
    if (j == 0) {
      float v = (acc + ldh(hs, (size_t)w * 32 + gf)) * dinv[w] + bgv;
      sth(gout, (size_t)w * 32 + gf, v);
    }
  }
}

// ---- scatter fallback ----
template <typename HT>
__global__ void k_scatter(const int* __restrict__ ei, int E,
                          const int* __restrict__ flag,
                          const HT* __restrict__ hs, float* __restrict__ gout) {
  long long gid = (long long)blockIdx.x * blockDim.x + threadIdx.x;
  int e = (int)(gid >> 3), part = (int)(gid & 7);
  if (e >= E) return;
  int is64 = *flag;
  int s = is64 ? ei[2 * e] : ei[e];
  int d = is64 ? ei[2 * (E + e)] : ei[E + e];
  int b = part * 4;
  float* gp = gout + (size_t)d * 32 + b;
  size_t hp = (size_t)s * 32 + b;
  atomicAdd(gp + 0, ldh(hs, hp + 0));
  atomicAdd(gp + 1, ldh(hs, hp + 1));
  atomicAdd(gp + 2, ldh(hs, hp + 2));
  atomicAdd(gp + 3, ldh(hs, hp + 3));
}
template <typename HT>
__global__ void k_finish(const HT* __restrict__ hs, const float* __restrict__ dinv,
                         const float* __restrict__ bg, float* __restrict__ gout,
                         int N) {
  int gid = blockIdx.x * blockDim.x + threadIdx.x;
  if (gid < N * 32) {
    int n = gid >> 5, g = gid & 31;
    gout[gid] = (gout[gid] + ldh(hs, (size_t)gid)) * dinv[n] + bg[g];
  }
}

// ============ weight image prep (exp2-prescaled) + rowst zeroing ============
__global__ void k_prep(const float* __restrict__ wih0, const float* __restrict__ whh0,
                       const float* __restrict__ wih1, const float* __restrict__ whh1,
                       const float* __restrict__ bih0, const float* __restrict__ bhh0,
                       const float* __restrict__ bih1, const float* __restrict__ bhh1,
                       const float* __restrict__ fcw, unsigned char* __restrict__ img,
                       int* __restrict__ rowst, int N) {
  int gid = blockIdx.x * blockDim.x + threadIdx.x;
  int nthr = gridDim.x * blockDim.x;
  for (int i = gid; i < N; i += nthr) rowst[i] = 0;
  {
    short* W = (short*)(img + OFF_WIH0);
    for (int i = gid; i < 208 * 32; i += nthr) {
      int row = i >> 5, k = i & 31, u = row >> 2, q = row & 3;
      float sc = (q == 2) ? 2.0f * L2E : -L2E;
      float v = (u < 50) ? wih0[(q * 50 + u) * 32 + k] * sc : 0.0f;
      W[row * 32 + (k ^ ((row & 3) << 3))] = f2bf(v);
    }
  }
  {
    short* W = (short*)(img + OFF_WHH0);
    for (int i = gid; i < 208 * 64; i += nthr) {
      int row = i >> 6, k = i & 63, u = row >> 2, q = row & 3;
      float sc = (q == 2) ? 2.0f * L2E : -L2E;
      float v = (u < 50 && k < 50) ? whh0[(q * 50 + u) * 50 + k] * sc : 0.0f;
      W[row * 64 + (k ^ ((row & 7) << 3))] = f2bf(v);
    }
  }
  {
    short* W = (short*)(img + OFF_WIH1);
    for (int i = gid; i < 208 * 64; i += nthr) {
      int row = i >> 6, k = i & 63, u = row >> 2, q = row & 3;
      float sc = (q == 2) ? 2.0f * L2E : -L2E;
      float v = (u < 50 && k < 50) ? wih1[(q * 50 + u) * 50 + k] * sc : 0.0f;
      W[row * 64 + (k ^ ((row & 7) << 3))] = f2bf(v);
    }
  }
  {
    short* W = (short*)(img + OFF_WHH1);
    for (int i = gid; i < 208 * 64; i += nthr) {
      int row = i >> 6, k = i & 63, u = row >> 2, q = row & 3;
      float sc = (q == 2) ? 2.0f * L2E : -L2E;
      float v = (u < 50 && k < 50) ? whh1[(q * 50 + u) * 50 + k] * sc : 0.0f;
      W[row * 64 + (k ^ ((row & 7) << 3))] = f2bf(v);
    }
  }
  {
    float* B = (float*)(img + OFF_B0);
    for (int i = gid; i < 208; i += nthr) {
      int u = i >> 2, q = i & 3;
      float sc = (q == 2) ? 2.0f * L2E : -L2E;
      B[i] = (u < 50) ? (bih0[q * 50 + u] + bhh0[q * 50 + u]) * sc : 0.0f;
    }
  }
  {
    float* B = (float*)(img + OFF_B1);
    for (int i = gid; i < 208; i += nthr) {
      int u = i >> 2, q = i & 3;
      float sc = (q == 2) ? 2.0f * L2E : -L2E;
      B[i] = (u < 50) ? (bih1[q * 50 + u] + bhh1[q * 50 + u]) * sc : 0.0f;
    }
  }
  {
    float* F = (float*)(img + OFF_FCW);
    for (int i = gid; i < 64; i += nthr) F[i] = (i < 50) ? fcw[i] : 0.0f;
  }
}

// exp2-domain gates, rcp-paired: 5 exp2 + 3 rcp
__device__ __forceinline__ float gate_update(const f32x4& acc, float& cp) {
  float ei = __builtin_amdgcn_exp2f(acc[0]);
  float ef = __builtin_amdgcn_exp2f(acc[1]);
  float eo = __builtin_amdgcn_exp2f(acc[3]);
  float eg = __builtin_amdgcn_exp2f(fminf(acc[2], 80.0f));
  float a = 1.0f + ei, b = 1.0f + ef;
  float rif = __builtin_amdgcn_rcpf(a * b);
  float iv = rif * b, fv = rif * a;
  float o1 = 1.0f + eo, g1 = eg + 1.0f;
  float rog = __builtin_amdgcn_rcpf(o1 * g1);
  float ov = rog * g1;
  float gv = (eg - 1.0f) * (rog * o1);
  float c = fv * cp + iv * gv;
  cp = c;
  float Ec = __builtin_amdgcn_exp2f(c * (2.0f * L2E));
  float th = (Ec - 1.0f) * __builtin_amdgcn_rcpf(Ec + 1.0f);
  return ov * th;
}

// ===== fused 2-layer MFMA LSTM: 16 waves x 16 nodes, 4 waves/SIMD =====
template <typename GT>
__global__ __launch_bounds__(1024, 1) void k_lstm(const GT* __restrict__ gout,
    const unsigned char* __restrict__ img, const float* __restrict__ fcb_p,
    float* __restrict__ out, int N) {
  __shared__ __align__(16) unsigned char smem[160640];  // 95104 img + 16*4096
  const int tid = threadIdx.x;
  {
    const uint4* s = (const uint4*)img;
    uint4* d = (uint4*)smem;
    for (int i = tid; i < IMG_BYTES / 16; i += 1024) d[i] = s[i];
  }
  __syncthreads();
  const int lane = tid & 63, wid = tid >> 6;       // wid 0..15
  const int l15 = lane & 15, l4 = lane >> 4;
  const int swz7 = (l15 & 7) << 3, swz3 = (l15 & 3) << 3;
  const int node0 = blockIdx.x * 256 + wid * 16;

  const short* WIH0 = (const short*)(smem + OFF_WIH0);
  const short* WHH0 = (const short*)(smem + OFF_WHH0);
  const short* WIH1 = (const short*)(smem + OFF_WIH1);
  const short* WHH1 = (const short*)(smem + OFF_WHH1);
  const float* B0   = (const float*)(smem + OFF_B0);
  const float* B1   = (const float*)(smem + OFF_B1);
  const float* FCW  = (const float*)(smem + OFF_FCW);
  short* h0st = (short*)(smem + IMG_BYTES + wid * 4096);  // [16][64] bf16, swz
  short* h1st = h0st + 1024;

  {  // zero both staging tiles (4096 B)
    uint4 z; z.x = z.y = z.z = z.w = 0u;
    uint4* p = (uint4*)h0st;
    for (int i = lane; i < 256; i += 64) p[i] = z;
  }

  // step-invariant input projection: p0r[t] = B0 + WIH0 . gnn  (once)
  f32x4 p0r[13];
  {
    short8 gfrag = {0, 0, 0, 0, 0, 0, 0, 0};
    int node = node0 + l15;
    if (node < N) gfrag = load_gfrag(gout, (size_t)node * 32 + l4 * 8);
#pragma unroll
    for (int t = 0; t < 13; ++t) {
      short8 w = *(const short8*)(WIH0 + (16 * t + l15) * 32 + ((l4 * 8) ^ swz3));
      f32x4 bv = *(const f32x4*)(B0 + t * 16 + l4 * 4);
      p0r[t] = __builtin_amdgcn_mfma_f32_16x16x32_bf16(w, gfrag, bv, 0, 0, 0);
    }
  }

  float c0[13], c1[13];
#pragma unroll
  for (int t = 0; t < 13; ++t) { c0[t] = 0.f; c1[t] = 0.f; }

#pragma unroll 1
  for (int s = 0; s < 10; ++s) {
    short8 h0f[2];
#pragma unroll
    for (int c = 0; c < 2; ++c)
      h0f[c] = *(const short8*)(h0st + l15 * 64 + ((c * 32 + l4 * 8) ^ swz7));
    // ---- layer 0 ----
#pragma unroll
    for (int t = 0; t < 13; ++t) {
      int arow = (16 * t + l15);
      short8 ah0 = *(const short8*)(WHH0 + arow * 64 + ((l4 * 8) ^ swz7));
      short8 ah1 = *(const short8*)(WHH0 + arow * 64 + ((32 + l4 * 8) ^ swz7));
      f32x4 acc = p0r[t];
      acc = __builtin_amdgcn_mfma_f32_16x16x32_bf16(ah0, h0f[0], acc, 0, 0, 0);
      acc = __builtin_amdgcn_mfma_f32_16x16x32_bf16(ah1, h0f[1], acc, 0, 0, 0);
      float h = gate_update(acc, c0[t]);
      h0st[l15 * 64 + ((4 * t + l4) ^ swz7)] = f2bf(h);
    }
    // re-read new h0 + old h1 as B-fragments (h1 loaded late: short live range)
    short8 h0nf[2], h1f[2];
#pragma unroll
    for (int c = 0; c < 2; ++c) {
      h0nf[c] = *(const short8*)(h0st + l15 * 64 + ((c * 32 + l4 * 8) ^ swz7));
      h1f[c]  = *(const short8*)(h1st + l15 * 64 + ((c * 32 + l4 * 8) ^ swz7));
    }
    // ---- layer 1 ----
#pragma unroll
    for (int t = 0; t < 13; ++t) {
      f32x4 bv = *(const f32x4*)(B1 + t * 16 + l4 * 4);
      int arow = (16 * t + l15);
      short8 ai0 = *(const short8*)(WIH1 + arow * 64 + ((l4 * 8) ^ swz7));
      short8 ai1 = *(const short8*)(WIH1 + arow * 64 + ((32 + l4 * 8) ^ swz7));
      short8 ah0 = *(const short8*)(WHH1 + arow * 64 + ((l4 * 8) ^ swz7));
      short8 ah1 = *(const short8*)(WHH1 + arow * 64 + ((32 + l4 * 8) ^ swz7));
      f32x4 acc = bv;
      acc = __builtin_amdgcn_mfma_f32_16x16x32_bf16(ai0, h0nf[0], acc, 0, 0, 0);
      acc = __builtin_amdgcn_mfma_f32_16x16x32_bf16(ai1, h0nf[1], acc, 0, 0, 0);
      acc = __builtin_amdgcn_mfma_f32_16x16x32_bf16(ah0, h1f[0], acc, 0, 0, 0);
      acc = __builtin_amdgcn_mfma_f32_16x16x32_bf16(ah1, h1f[1], acc, 0, 0, 0);
      float h = gate_update(acc, c1[t]);
      h1st[l15 * 64 + ((4 * t + l4) ^ swz7)] = f2bf(h);
    }
  }
  // ---- FC epilogue from final h1 staging (FCW zero-padded to 64) ----
  float fcb = fcb_p[0];
  float facc = 0.f;
#pragma unroll
  for (int c = 0; c < 2; ++c) {
    short8 f = *(const short8*)(h1st + l15 * 64 + ((c * 32 + l4 * 8) ^ swz7));
#pragma unroll
    for (int j = 0; j < 8; ++j)
      facc += b2f(f[j]) * FCW[c * 32 + l4 * 8 + j];
  }
  facc += __shfl_xor(facc, 16);
  facc += __shfl_xor(facc, 32);
  int node = node0 + l15;
  if (l4 == 0 && node < N) out[node] = facc + fcb;
}

// ================= host launcher =================
extern "C" void kernel_launch(void* const* d_in, const int* in_sizes, int n_in,
                              void* d_out, int out_size, void* d_ws, size_t ws_size,
                              hipStream_t stream) {
  const float* x    = (const float*)d_in[0];
  const float* Wg   = (const float*)d_in[1];
  const float* bg   = (const float*)d_in[2];
  const float* wih0 = (const float*)d_in[3];
  const float* whh0 = (const float*)d_in[4];
  const float* bih0 = (const float*)d_in[5];
  const float* bhh0 = (const float*)d_in[6];
  const float* wih1 = (const float*)d_in[7];
  const float* whh1 = (const float*)d_in[8];
  const float* bih1 = (const float*)d_in[9];
  const float* bhh1 = (const float*)d_in[10];
  const float* fcw  = (const float*)d_in[11];
  const float* fcb  = (const float*)d_in[12];
  const int*   edge = (const int*)d_in[13];
  int N = in_sizes[0] / 128;
  int E = in_sizes[13] / 2;

  char* ws = (char*)d_ws;
  size_t off = 0;
  auto take = [&](size_t b) {
    size_t o = off;
    off = (off + b + 255) & ~(size_t)255;
    return o;
  };
  int*   rowst = (int*)(ws + take((size_t)N * 4));
  float* dinv  = (float*)(ws + take((size_t)N * 4));
  int*   flag  = (int*)(ws + take(256));
  unsigned char* wimg = (unsigned char*)(ws + take(IMG_BYTES));
  size_t base = off;

  const int NP = 4;
  int span = (N + NP - 1) / NP;
  bool canU16 = (N <= 65535) && (E <= 100000000);

  size_t csr_b  = ((size_t)E * 2 + 255) & ~(size_t)255;
  size_t hsb    = ((size_t)N * 64 + 255) & ~(size_t)255;
  size_t reg2_b = (size_t)E * 4 > 2 * hsb ? (size_t)E * 4 : 2 * hsb;
  size_t needP  = base + csr_b + reg2_b;
  size_t needA = base + (((size_t)N * 128 + 255) & ~(size_t)255)
               + (((size_t)E * 4 + 255) & ~(size_t)255)
               + ((size_t)N * 128);

  // prep also zeros rowst (must precede count/convert)
  k_prep<<<52, 256, 0, stream>>>(wih0, whh0, wih1, whh1, bih0, bhh0, bih1, bhh1,
                                 fcw, wimg, rowst, N);

  if (canU16 && ws_size >= needP) {
    // ---- path P: packed edges, u16 csr, bf16 hs/gout (split kernels) ----
    unsigned short* csr = (unsigned short*)(ws + take(csr_b));
    char* reg2 = ws + take(reg2_b);
    unsigned int*   ed   = (unsigned int*)reg2;
    __hip_bfloat16* hs   = (__hip_bfloat16*)reg2;
    __hip_bfloat16* gout = (__hip_bfloat16*)(reg2 + hsb);
    int* bsum = (int*)csr;  // transient alias (scan before fill)

    k_convert<<<(E + 255) / 256, 256, 0, stream>>>(edge, E, ed, rowst);
    k_scanA<<<SCAN_B, 256, 0, stream>>>(rowst, dinv, bsum, N);
    k_scanB<<<SCAN_B, 256, 0, stream>>>(rowst, bsum, N);
    for (int p = 0; p < NP; ++p) {
      int lo = p * span, hi = min(lo + span, N);
      if (lo >= hi) break;
      k_fill_p<<<(E + 255) / 256, 256, 0, stream>>>(ed, E, rowst, csr, lo, hi);
    }
    k_hs<__hip_bfloat16><<<(N + 63) / 64, 256, 0, stream>>>(x, Wg, dinv, hs, N);
    int gwaves = (N + 3) / 4;
    k_gather4<__hip_bfloat16, __hip_bfloat16, unsigned short>
        <<<(gwaves * 64 + 255) / 256, 256, 0, stream>>>(csr, rowst, hs, dinv,
                                                        bg, gout, N);
    k_lstm<__hip_bfloat16><<<(N + 255) / 256, 1024, 0, stream>>>(gout, wimg, fcb,
                                                                 (float*)d_out, N);
  } else if (ws_size >= needA) {
    // ---- path A: f32 everything, u32 csr ----
    float* gout = (float*)(ws + take((size_t)N * 128));
    int*   csr  = (int*)(ws + take((size_t)E * 4));
    float* hs   = (float*)(ws + take((size_t)N * 128));
    int*   bsum = (int*)csr;
    k_detect<<<1, 1, 0, stream>>>(edge, E, flag);
    k_count<<<(E + 255) / 256, 256, 0, stream>>>(edge, E, flag, rowst);
    k_scanA<<<SCAN_B, 256, 0, stream>>>(rowst, dinv, bsum, N);
    k_scanB<<<SCAN_B, 256, 0, stream>>>(rowst, bsum, N);
    k_hs<float><<<(N + 63) / 64, 256, 0, stream>>>(x, Wg, dinv, hs, N);
    for (int p = 0; p < NP; ++p) {
      int lo = p * span, hi = min(lo + span, N);
      if (lo >= hi) break;
      k_fill<int><<<(E + 255) / 256, 256, 0, stream>>>(edge, E, flag, rowst,
                                                       csr, lo, hi);
    }
    int gwaves = (N + 3) / 4;
    k_gather4<float, float, int><<<(gwaves * 64 + 255) / 256, 256, 0, stream>>>(
        csr, rowst, hs, dinv, bg, gout, N);
    k_lstm<float><<<(N + 255) / 256, 1024, 0, stream>>>(gout, wimg, fcb,
                                                        (float*)d_out, N);
  } else {
    // ---- path C: scatter fallback ----
    float* gout = (float*)(ws + take((size_t)N * 128));
    __hip_bfloat16* hs = (__hip_bfloat16*)(ws + take((size_t)N * 64));
    hipMemsetAsync(gout, 0, (size_t)N * 128, stream);
    k_detect<<<1, 1, 0, stream>>>(edge, E, flag);
    k_count<<<(E + 255) / 256, 256, 0, stream>>>(edge, E, flag, rowst);
    k_dinv<<<(N + 255) / 256, 256, 0, stream>>>(rowst, dinv, N);
    k_hs<__hip_bfloat16><<<(N + 63) / 64, 256, 0, stream>>>(x, Wg, dinv, hs, N);
    int sc_blocks = (int)(((long long)E * 8 + 255) / 256);
    k_scatter<__hip_bfloat16><<<sc_blocks, 256, 0, stream>>>(edge, E, flag, hs, gout);
    k_finish<__hip_bfloat16><<<(N * 32 + 255) / 256, 256, 0, stream>>>(
        hs, dinv, bg, gout, N);
    k_lstm<float><<<(N + 255) / 256, 1024, 0, stream>>>(gout, wimg, fcb,
                                                        (float*)d_out, N);
  }
}

// Round 15
// 327.293 us; speedup vs baseline: 1.0015x; 1.0015x over previous
//
#include <hip/hip_runtime.h>
#include <hip/hip_bf16.h>

typedef __attribute__((ext_vector_type(8))) short short8;
typedef __attribute__((ext_vector_type(4))) float f32x4;

#define L2E 1.442695041f
#define SCAN_B 256

__device__ __forceinline__ short f2bf(float f) {
  union { __hip_bfloat16 b; short s; } u;
  u.b = __float2bfloat16(f);
  return u.s;
}
__device__ __forceinline__ float b2f(short s) {
  unsigned u = ((unsigned)(unsigned short)s) << 16;
  return __uint_as_float(u);
}

// ---- f32/bf16 storage accessors ----
__device__ __forceinline__ float ldh(const float* p, size_t i) { return p[i]; }
__device__ __forceinline__ float ldh(const __hip_bfloat16* p, size_t i) {
  return __bfloat162float(p[i]);
}
__device__ __forceinline__ void sth(float* p, size_t i, float v) { p[i] = v; }
__device__ __forceinline__ void sth(__hip_bfloat16* p, size_t i, float v) {
  p[i] = __float2bfloat16(v);
}

__device__ __forceinline__ short8 load_gfrag(const float* g, size_t base) {
  const float4* gp = (const float4*)(g + base);
  float4 a = gp[0], b = gp[1];
  short8 t;
  t[0]=f2bf(a.x); t[1]=f2bf(a.y); t[2]=f2bf(a.z); t[3]=f2bf(a.w);
  t[4]=f2bf(b.x); t[5]=f2bf(b.y); t[6]=f2bf(b.z); t[7]=f2bf(b.w);
  return t;
}
__device__ __forceinline__ short8 load_gfrag(const __hip_bfloat16* g, size_t base) {
  return *(const short8*)(g + base);
}

// ---------------- weight image layout (bytes) ----------------
#define OFF_WIH0 0        // bf16 [208][32], swz (row&3)<<3, exp2-prescaled
#define OFF_WHH0 13312    // bf16 [208][64], swz (row&7)<<3, exp2-prescaled
#define OFF_WIH1 39936
#define OFF_WHH1 66560
#define OFF_B0   93184    // f32 [208], exp2-prescaled
#define OFF_B1   94016
#define OFF_FCW  94848    // f32 [64] (raw, zero-padded 50..63)
#define IMG_BYTES 95104

// ================= edge dtype autodetect (A/C paths) =================
__global__ void k_detect(const int* __restrict__ ei, int E, int* __restrict__ flag) {
  if (threadIdx.x == 0 && blockIdx.x == 0) {
    int odd_nz = 0, even_nz = 0;
    int m = min(128, E);
    for (int i = 0; i < m; ++i) {
      odd_nz |= (ei[2 * i + 1] != 0);
      even_nz |= (ei[2 * i] != 0);
    }
    *flag = (even_nz && !odd_nz) ? 1 : 0;
  }
}

// ================= GCN =================

__global__ void k_count(const int* __restrict__ ei, int E,
                        const int* __restrict__ flag, int* __restrict__ cnt) {
  int e = blockIdx.x * blockDim.x + threadIdx.x;
  if (e < E) {
    int d = (*flag) ? ei[2 * (E + e)] : ei[E + e];
    atomicAdd(&cnt[d], 1);
  }
}

// read edges once: block-local dtype detect + packed emit + count atomics
__global__ void k_convert(const int* __restrict__ ei, int E,
                          unsigned int* __restrict__ ed, int* __restrict__ cnt) {
  __shared__ int sflag;
  if (threadIdx.x == 0) {
    int odd_nz = 0, even_nz = 0;
    int m = min(128, E);
    for (int i = 0; i < m; ++i) {
      odd_nz |= (ei[2 * i + 1] != 0);
      even_nz |= (ei[2 * i] != 0);
    }
    sflag = (even_nz && !odd_nz) ? 1 : 0;
  }
  __syncthreads();
  int is64 = sflag;
  int e = blockIdx.x * blockDim.x + threadIdx.x;
  if (e < E) {
    int s = is64 ? ei[2 * e] : ei[e];
    int d = is64 ? ei[2 * (E + e)] : ei[E + e];
    ed[e] = (unsigned int)s | ((unsigned int)d << 16);
    atomicAdd(&cnt[d], 1);
  }
}

__global__ void k_dinv(const int* __restrict__ cnt, float* __restrict__ dinv, int N) {
  int i = blockIdx.x * blockDim.x + threadIdx.x;
  if (i < N) dinv[i] = rsqrtf((float)cnt[i] + 1.0f);
}

// ---- grid-parallel scan, stage A: per-block sums (+dinv emission) ----
__global__ __launch_bounds__(256) void k_scanA(const int* __restrict__ cnt,
                                               float* __restrict__ dinv,
                                               int* __restrict__ bsum, int N) {
  __shared__ int red[256];
  int b = blockIdx.x, t = threadIdx.x;
  int chunk = (N + SCAN_B - 1) / SCAN_B;
  int lo = b * chunk, hi = min(lo + chunk, N);
  int s = 0;
  for (int i = lo + t; i < hi; i += 256) {
    int c = cnt[i];
    dinv[i] = rsqrtf((float)c + 1.0f);
    s += c;
  }
  red[t] = s;
  __syncthreads();
  for (int o = 128; o > 0; o >>= 1) {
    if (t < o) red[t] += red[t + o];
    __syncthreads();
  }
  if (t == 0) bsum[b] = red[0];
}

// ---- stage B: block base from bsum-scan, then tiled in-place excl scan ----
__global__ __launch_bounds__(256) void k_scanB(int* __restrict__ a,
                                               const int* __restrict__ bsum,
                                               int N) {
  __shared__ int sh[256];
  int b = blockIdx.x, t = threadIdx.x;
  int chunk = (N + SCAN_B - 1) / SCAN_B;
  int lo = b * chunk, hi = min(lo + chunk, N);
  sh[t] = bsum[t];
  __syncthreads();
  for (int o = 1; o < 256; o <<= 1) {
    int u = (t >= o) ? sh[t - o] : 0;
    __syncthreads();
    sh[t] += u;
    __syncthreads();
  }
  int carry = (b == 0) ? 0 : sh[b - 1];
  __syncthreads();
  for (int i0 = lo; i0 < hi; i0 += 256) {
    int i = i0 + t;
    int c = (i < hi) ? a[i] : 0;
    sh[t] = c;
    __syncthreads();
    for (int o = 1; o < 256; o <<= 1) {
      int u = (t >= o) ? sh[t - o] : 0;
      __syncthreads();
      sh[t] += u;
      __syncthreads();
    }
    if (i < hi) a[i] = carry + sh[t] - c;  // exclusive
    carry += sh[255];
    __syncthreads();
  }
}

// packed fill pass: dst-range window keeps csr writes L2-coalesced
__global__ void k_fill_p(const unsigned int* __restrict__ ed, int E,
                         int* __restrict__ rowst,
                         unsigned short* __restrict__ csr, int lo, int hi) {
  int e = blockIdx.x * blockDim.x + threadIdx.x;
  if (e < E) {
    unsigned int v = ed[e];
    int d = (int)(v >> 16);
    if (d >= lo && d < hi) {
      int p = atomicAdd(&rowst[d], 1);
      csr[p] = (unsigned short)(v & 0xFFFFu);
    }
  }
}

// legacy fill (path A)
template <typename CT>
__global__ void k_fill(const int* __restrict__ ei, int E,
                       const int* __restrict__ flag,
                       int* __restrict__ rowst, CT* __restrict__ csr,
                       int lo, int hi) {
  int e = blockIdx.x * blockDim.x + threadIdx.x;
  if (e < E) {
    int is64 = *flag;
    int d = is64 ? ei[2 * (E + e)] : ei[E + e];
    if (d >= lo && d < hi) {
      int s = is64 ? ei[2 * e] : ei[e];
      int p = atomicAdd(&rowst[d], 1);
      csr[p] = (CT)s;
    }
  }
}

// hs[n][g] = (x[n] @ W)[g] * dinv[n]
template <typename HT>
__global__ __launch_bounds__(256) void k_hs(const float* __restrict__ x,
                                            const float* __restrict__ Wg,
                                            const float* __restrict__ dinv,
                                            HT* __restrict__ hs, int N) {
  __shared__ __align__(16) float xt[64][132];
  __shared__ __align__(16) float Wl[128][32];
  int tid = threadIdx.x;
  int nb = blockIdx.x * 64;
  for (int i = tid; i < 4096; i += 256) Wl[i >> 5][i & 31] = Wg[i];
  const float4* xv = (const float4*)x;
  for (int i = tid; i < 2048; i += 256) {
    int r = i >> 5, c = i & 31;
    float4 v = make_float4(0.f, 0.f, 0.f, 0.f);
    if (nb + r < N) v = xv[(size_t)(nb + r) * 32 + c];
    *(float4*)&xt[r][c * 4] = v;
  }
  __syncthreads();
  int nl = tid >> 2, gq = (tid & 3) * 8;
  float a[8];
#pragma unroll
  for (int j = 0; j < 8; ++j) a[j] = 0.f;
  for (int k = 0; k < 128; ++k) {
    float xk = xt[nl][k];
#pragma unroll
    for (int j = 0; j < 8; ++j) a[j] += xk * Wl[k][gq + j];
  }
  int n = nb + nl;
  if (n < N) {
    float d = dinv[n];
#pragma unroll
    for (int j = 0; j < 8; ++j) sth(hs, (size_t)n * 32 + gq + j, a[j] * d);
  }
}

// 4 nodes per wave; batched rowst window load + 4 prefetched idx loads
template <typename HT, typename GT, typename CT>
__global__ void k_gather4(const CT* __restrict__ csr, const int* __restrict__ rowst,
                          const HT* __restrict__ hs, const float* __restrict__ dinv,
                          const float* __restrict__ bg, GT* __restrict__ gout,
                          int N) {
  long long gtid = (long long)blockIdx.x * blockDim.x + threadIdx.x;
  int wave = (int)(gtid >> 6);
  int n0 = wave * 4;
  if (n0 >= N) return;
  int l = threadIdx.x & 63;
  int gf = l & 31, j = l >> 5;
  // lanes 0..4 hold rowst[n0-1 .. n0+3] (0 when OOB)
  int rr = 0;
  int ri = n0 - 1 + l;
  if (l <= 4 && ri >= 0 && ri < N) rr = rowst[ri];
  int st[4], en[4], idx[4], deg[4];
#pragma unroll
  for (int q = 0; q < 4; ++q) {
    st[q] = __shfl(rr, q);
    en[q] = __shfl(rr, q + 1);
    deg[q] = en[q] - st[q];
  }
#pragma unroll
  for (int q = 0; q < 4; ++q)
    idx[q] = (n0 + q < N && l < deg[q]) ? (int)csr[st[q] + l] : 0;
  float bgv = bg[gf];
#pragma unroll
  for (int q = 0; q < 4; ++q) {
    int w = n0 + q;
    if (w >= N) break;
    float acc = 0.f;
    int dm = min(deg[q], 64);
#pragma unroll 1
    for (int base = 0; base < 64; base += 16) {
      if (base >= dm) break;
#pragma unroll
      for (int i = 0; i < 8; ++i) {
        int e = base + 2 * i + j;
        int src = __shfl(idx[q], e);
        float v = ldh(hs, (size_t)src * 32 + gf);
        acc += (e < dm) ? v : 0.f;
      }
    }
    for (int k2 = st[q] + 64 + j; k2 < en[q]; k2 += 2)
      acc += ldh(hs, (size_t)csr[k2] * 32 + gf);
    acc += __shfl_xor(acc, 32);
    if (j == 0) {
      float v = (acc + ldh(hs, (size_t)w * 32 + gf)) * dinv[w] + bgv;
      sth(gout, (size_t)w * 32 + gf, v);
    }
  }
}

// ---- scatter fallback ----
template <typename HT>
__global__ void k_scatter(const int* __restrict__ ei, int E,
                          const int* __restrict__ flag,
                          const HT* __restrict__ hs, float* __restrict__ gout) {
  long long gid = (long long)blockIdx.x * blockDim.x + threadIdx.x;
  int e = (int)(gid >> 3), part = (int)(gid & 7);
  if (e >= E) return;
  int is64 = *flag;
  int s = is64 ? ei[2 * e] : ei[e];
  int d = is64 ? ei[2 * (E + e)] : ei[E + e];
  int b = part * 4;
  float* gp = gout + (size_t)d * 32 + b;
  size_t hp = (size_t)s * 32 + b;
  atomicAdd(gp + 0, ldh(hs, hp + 0));
  atomicAdd(gp + 1, ldh(hs, hp + 1));
  atomicAdd(gp + 2, ldh(hs, hp + 2));
  atomicAdd(gp + 3, ldh(hs, hp + 3));
}
template <typename HT>
__global__ void k_finish(const HT* __restrict__ hs, const float* __restrict__ dinv,
                         const float* __restrict__ bg, float* __restrict__ gout,
                         int N) {
  int gid = blockIdx.x * blockDim.x + threadIdx.x;
  if (gid < N * 32) {
    int n = gid >> 5, g = gid & 31;
    gout[gid] = (gout[gid] + ldh(hs, (size_t)gid)) * dinv[n] + bg[g];
  }
}

// ============ weight image prep (exp2-prescaled) + rowst zeroing ============
__global__ void k_prep(const float* __restrict__ wih0, const float* __restrict__ whh0,
                       const float* __restrict__ wih1, const float* __restrict__ whh1,
                       const float* __restrict__ bih0, const float* __restrict__ bhh0,
                       const float* __restrict__ bih1, const float* __restrict__ bhh1,
                       const float* __restrict__ fcw, unsigned char* __restrict__ img,
                       int* __restrict__ rowst, int N) {
  int gid = blockIdx.x * blockDim.x + threadIdx.x;
  int nthr = gridDim.x * blockDim.x;
  for (int i = gid; i < N; i += nthr) rowst[i] = 0;
  {
    short* W = (short*)(img + OFF_WIH0);
    for (int i = gid; i < 208 * 32; i += nthr) {
      int row = i >> 5, k = i & 31, u = row >> 2, q = row & 3;
      float sc = (q == 2) ? 2.0f * L2E : -L2E;
      float v = (u < 50) ? wih0[(q * 50 + u) * 32 + k] * sc : 0.0f;
      W[row * 32 + (k ^ ((row & 3) << 3))] = f2bf(v);
    }
  }
  {
    short* W = (short*)(img + OFF_WHH0);
    for (int i = gid; i < 208 * 64; i += nthr) {
      int row = i >> 6, k = i & 63, u = row >> 2, q = row & 3;
      float sc = (q == 2) ? 2.0f * L2E : -L2E;
      float v = (u < 50 && k < 50) ? whh0[(q * 50 + u) * 50 + k] * sc : 0.0f;
      W[row * 64 + (k ^ ((row & 7) << 3))] = f2bf(v);
    }
  }
  {
    short* W = (short*)(img + OFF_WIH1);
    for (int i = gid; i < 208 * 64; i += nthr) {
      int row = i >> 6, k = i & 63, u = row >> 2, q = row & 3;
      float sc = (q == 2) ? 2.0f * L2E : -L2E;
      float v = (u < 50 && k < 50) ? wih1[(q * 50 + u) * 50 + k] * sc : 0.0f;
      W[row * 64 + (k ^ ((row & 7) << 3))] = f2bf(v);
    }
  }
  {
    short* W = (short*)(img + OFF_WHH1);
    for (int i = gid; i < 208 * 64; i += nthr) {
      int row = i >> 6, k = i & 63, u = row >> 2, q = row & 3;
      float sc = (q == 2) ? 2.0f * L2E : -L2E;
      float v = (u < 50 && k < 50) ? whh1[(q * 50 + u) * 50 + k] * sc : 0.0f;
      W[row * 64 + (k ^ ((row & 7) << 3))] = f2bf(v);
    }
  }
  {
    float* B = (float*)(img + OFF_B0);
    for (int i = gid; i < 208; i += nthr) {
      int u = i >> 2, q = i & 3;
      float sc = (q == 2) ? 2.0f * L2E : -L2E;
      B[i] = (u < 50) ? (bih0[q * 50 + u] + bhh0[q * 50 + u]) * sc : 0.0f;
    }
  }
  {
    float* B = (float*)(img + OFF_B1);
    for (int i = gid; i < 208; i += nthr) {
      int u = i >> 2, q = i & 3;
      float sc = (q == 2) ? 2.0f * L2E : -L2E;
      B[i] = (u < 50) ? (bih1[q * 50 + u] + bhh1[q * 50 + u]) * sc : 0.0f;
    }
  }
  {
    float* F = (float*)(img + OFF_FCW);
    for (int i = gid; i < 64; i += nthr) F[i] = (i < 50) ? fcw[i] : 0.0f;
  }
}

// exp2-domain gates, rcp-paired: 5 exp2 + 3 rcp
__device__ __forceinline__ float gate_update(const f32x4& acc, float& cp) {
  float ei = __builtin_amdgcn_exp2f(acc[0]);
  float ef = __builtin_amdgcn_exp2f(acc[1]);
  float eo = __builtin_amdgcn_exp2f(acc[3]);
  float eg = __builtin_amdgcn_exp2f(fminf(acc[2], 80.0f));
  float a = 1.0f + ei, b = 1.0f + ef;
  float rif = __builtin_amdgcn_rcpf(a * b);
  float iv = rif * b, fv = rif * a;
  float o1 = 1.0f + eo, g1 = eg + 1.0f;
  float rog = __builtin_amdgcn_rcpf(o1 * g1);
  float ov = rog * g1;
  float gv = (eg - 1.0f) * (rog * o1);
  float c = fv * cp + iv * gv;
  cp = c;
  float Ec = __builtin_amdgcn_exp2f(c * (2.0f * L2E));
  float th = (Ec - 1.0f) * __builtin_amdgcn_rcpf(Ec + 1.0f);
  return ov * th;
}

// ===== fused 2-layer MFMA LSTM: 16 waves x 16 nodes, 4 waves/SIMD =====
// __launch_bounds__(1024, 4): min 4 waves/EU -> VGPR budget 128 (no spill;
// r14's (1024,1) let the allocator target 64 VGPR -> 50-reg spill, FETCH 30MB)
template <typename GT>
__global__ __launch_bounds__(1024, 4) void k_lstm(const GT* __restrict__ gout,
    const unsigned char* __restrict__ img, const float* __restrict__ fcb_p,
    float* __restrict__ out, int N) {
  __shared__ __align__(16) unsigned char smem[160640];  // 95104 img + 16*4096
  const int tid = threadIdx.x;
  {
    const uint4* s = (const uint4*)img;
    uint4* d = (uint4*)smem;
    for (int i = tid; i < IMG_BYTES / 16; i += 1024) d[i] = s[i];
  }
  __syncthreads();
  const int lane = tid & 63, wid = tid >> 6;       // wid 0..15
  const int l15 = lane & 15, l4 = lane >> 4;
  const int swz7 = (l15 & 7) << 3, swz3 = (l15 & 3) << 3;
  const int node0 = blockIdx.x * 256 + wid * 16;

  const short* WIH0 = (const short*)(smem + OFF_WIH0);
  const short* WHH0 = (const short*)(smem + OFF_WHH0);
  const short* WIH1 = (const short*)(smem + OFF_WIH1);
  const short* WHH1 = (const short*)(smem + OFF_WHH1);
  const float* B0   = (const float*)(smem + OFF_B0);
  const float* B1   = (const float*)(smem + OFF_B1);
  const float* FCW  = (const float*)(smem + OFF_FCW);
  short* h0st = (short*)(smem + IMG_BYTES + wid * 4096);  // [16][64] bf16, swz
  short* h1st = h0st + 1024;

  {  // zero both staging tiles (4096 B)
    uint4 z; z.x = z.y = z.z = z.w = 0u;
    uint4* p = (uint4*)h0st;
    for (int i = lane; i < 256; i += 64) p[i] = z;
  }

  // step-invariant input projection: p0r[t] = B0 + WIH0 . gnn  (once)
  f32x4 p0r[13];
  {
    short8 gfrag = {0, 0, 0, 0, 0, 0, 0, 0};
    int node = node0 + l15;
    if (node < N) gfrag = load_gfrag(gout, (size_t)node * 32 + l4 * 8);
#pragma unroll
    for (int t = 0; t < 13; ++t) {
      short8 w = *(const short8*)(WIH0 + (16 * t + l15) * 32 + ((l4 * 8) ^ swz3));
      f32x4 bv = *(const f32x4*)(B0 + t * 16 + l4 * 4);
      p0r[t] = __builtin_amdgcn_mfma_f32_16x16x32_bf16(w, gfrag, bv, 0, 0, 0);
    }
  }

  float c0[13], c1[13];
#pragma unroll
  for (int t = 0; t < 13; ++t) { c0[t] = 0.f; c1[t] = 0.f; }

#pragma unroll 1
  for (int s = 0; s < 10; ++s) {
    short8 h0f[2];
#pragma unroll
    for (int c = 0; c < 2; ++c)
      h0f[c] = *(const short8*)(h0st + l15 * 64 + ((c * 32 + l4 * 8) ^ swz7));
    // ---- layer 0 ----
#pragma unroll
    for (int t = 0; t < 13; ++t) {
      int arow = (16 * t + l15);
      short8 ah0 = *(const short8*)(WHH0 + arow * 64 + ((l4 * 8) ^ swz7));
      short8 ah1 = *(const short8*)(WHH0 + arow * 64 + ((32 + l4 * 8) ^ swz7));
      f32x4 acc = p0r[t];
      acc = __builtin_amdgcn_mfma_f32_16x16x32_bf16(ah0, h0f[0], acc, 0, 0, 0);
      acc = __builtin_amdgcn_mfma_f32_16x16x32_bf16(ah1, h0f[1], acc, 0, 0, 0);
      float h = gate_update(acc, c0[t]);
      h0st[l15 * 64 + ((4 * t + l4) ^ swz7)] = f2bf(h);
    }
    // re-read new h0 + old h1 as B-fragments (h1 loaded late: short live range)
    short8 h0nf[2], h1f[2];
#pragma unroll
    for (int c = 0; c < 2; ++c) {
      h0nf[c] = *(const short8*)(h0st + l15 * 64 + ((c * 32 + l4 * 8) ^ swz7));
      h1f[c]  = *(const short8*)(h1st + l15 * 64 + ((c * 32 + l4 * 8) ^ swz7));
    }
    // ---- layer 1 ----
#pragma unroll
    for (int t = 0; t < 13; ++t) {
      f32x4 bv = *(const f32x4*)(B1 + t * 16 + l4 * 4);
      int arow = (16 * t + l15);
      short8 ai0 = *(const short8*)(WIH1 + arow * 64 + ((l4 * 8) ^ swz7));
      short8 ai1 = *(const short8*)(WIH1 + arow * 64 + ((32 + l4 * 8) ^ swz7));
      short8 ah0 = *(const short8*)(WHH1 + arow * 64 + ((l4 * 8) ^ swz7));
      short8 ah1 = *(const short8*)(WHH1 + arow * 64 + ((32 + l4 * 8) ^ swz7));
      f32x4 acc = bv;
      acc = __builtin_amdgcn_mfma_f32_16x16x32_bf16(ai0, h0nf[0], acc, 0, 0, 0);
      acc = __builtin_amdgcn_mfma_f32_16x16x32_bf16(ai1, h0nf[1], acc, 0, 0, 0);
      acc = __builtin_amdgcn_mfma_f32_16x16x32_bf16(ah0, h1f[0], acc, 0, 0, 0);
      acc = __builtin_amdgcn_mfma_f32_16x16x32_bf16(ah1, h1f[1], acc, 0, 0, 0);
      float h = gate_update(acc, c1[t]);
      h1st[l15 * 64 + ((4 * t + l4) ^ swz7)] = f2bf(h);
    }
  }
  // ---- FC epilogue from final h1 staging (FCW zero-padded to 64) ----
  float fcb = fcb_p[0];
  float facc = 0.f;
#pragma unroll
  for (int c = 0; c < 2; ++c) {
    short8 f = *(const short8*)(h1st + l15 * 64 + ((c * 32 + l4 * 8) ^ swz7));
#pragma unroll
    for (int j = 0; j < 8; ++j)
      facc += b2f(f[j]) * FCW[c * 32 + l4 * 8 + j];
  }
  facc += __shfl_xor(facc, 16);
  facc += __shfl_xor(facc, 32);
  int node = node0 + l15;
  if (l4 == 0 && node < N) out[node] = facc + fcb;
}

// ================= host launcher =================
extern "C" void kernel_launch(void* const* d_in, const int* in_sizes, int n_in,
                              void* d_out, int out_size, void* d_ws, size_t ws_size,
                              hipStream_t stream) {
  const float* x    = (const float*)d_in[0];
  const float* Wg   = (const float*)d_in[1];
  const float* bg   = (const float*)d_in[2];
  const float* wih0 = (const float*)d_in[3];
  const float* whh0 = (const float*)d_in[4];
  const float* bih0 = (const float*)d_in[5];
  const float* bhh0 = (const float*)d_in[6];
  const float* wih1 = (const float*)d_in[7];
  const float* whh1 = (const float*)d_in[8];
  const float* bih1 = (const float*)d_in[9];
  const float* bhh1 = (const float*)d_in[10];
  const float* fcw  = (const float*)d_in[11];
  const float* fcb  = (const float*)d_in[12];
  const int*   edge = (const int*)d_in[13];
  int N = in_sizes[0] / 128;
  int E = in_sizes[13] / 2;

  char* ws = (char*)d_ws;
  size_t off = 0;
  auto take = [&](size_t b) {
    size_t o = off;
    off = (off + b + 255) & ~(size_t)255;
    return o;
  };
  int*   rowst = (int*)(ws + take((size_t)N * 4));
  float* dinv  = (float*)(ws + take((size_t)N * 4));
  int*   flag  = (int*)(ws + take(256));
  unsigned char* wimg = (unsigned char*)(ws + take(IMG_BYTES));
  size_t base = off;

  const int NP = 4;
  int span = (N + NP - 1) / NP;
  bool canU16 = (N <= 65535) && (E <= 100000000);

  size_t csr_b  = ((size_t)E * 2 + 255) & ~(size_t)255;
  size_t hsb    = ((size_t)N * 64 + 255) & ~(size_t)255;
  size_t reg2_b = (size_t)E * 4 > 2 * hsb ? (size_t)E * 4 : 2 * hsb;
  size_t needP  = base + csr_b + reg2_b;
  size_t needA = base + (((size_t)N * 128 + 255) & ~(size_t)255)
               + (((size_t)E * 4 + 255) & ~(size_t)255)
               + ((size_t)N * 128);

  // prep also zeros rowst (must precede count/convert)
  k_prep<<<52, 256, 0, stream>>>(wih0, whh0, wih1, whh1, bih0, bhh0, bih1, bhh1,
                                 fcw, wimg, rowst, N);

  if (canU16 && ws_size >= needP) {
    // ---- path P: packed edges, u16 csr, bf16 hs/gout (split kernels) ----
    unsigned short* csr = (unsigned short*)(ws + take(csr_b));
    char* reg2 = ws + take(reg2_b);
    unsigned int*   ed   = (unsigned int*)reg2;
    __hip_bfloat16* hs   = (__hip_bfloat16*)reg2;
    __hip_bfloat16* gout = (__hip_bfloat16*)(reg2 + hsb);
    int* bsum = (int*)csr;  // transient alias (scan before fill)

    k_convert<<<(E + 255) / 256, 256, 0, stream>>>(edge, E, ed, rowst);
    k_scanA<<<SCAN_B, 256, 0, stream>>>(rowst, dinv, bsum, N);
    k_scanB<<<SCAN_B, 256, 0, stream>>>(rowst, bsum, N);
    for (int p = 0; p < NP; ++p) {
      int lo = p * span, hi = min(lo + span, N);
      if (lo >= hi) break;
      k_fill_p<<<(E + 255) / 256, 256, 0, stream>>>(ed, E, rowst, csr, lo, hi);
    }
    k_hs<__hip_bfloat16><<<(N + 63) / 64, 256, 0, stream>>>(x, Wg, dinv, hs, N);
    int gwaves = (N + 3) / 4;
    k_gather4<__hip_bfloat16, __hip_bfloat16, unsigned short>
        <<<(gwaves * 64 + 255) / 256, 256, 0, stream>>>(csr, rowst, hs, dinv,
                                                        bg, gout, N);
    k_lstm<__hip_bfloat16><<<(N + 255) / 256, 1024, 0, stream>>>(gout, wimg, fcb,
                                                                 (float*)d_out, N);
  } else if (ws_size >= needA) {
    // ---- path A: f32 everything, u32 csr ----
    float* gout = (float*)(ws + take((size_t)N * 128));
    int*   csr  = (int*)(ws + take((size_t)E * 4));
    float* hs   = (float*)(ws + take((size_t)N * 128));
    int*   bsum = (int*)csr;
    k_detect<<<1, 1, 0, stream>>>(edge, E, flag);
    k_count<<<(E + 255) / 256, 256, 0, stream>>>(edge, E, flag, rowst);
    k_scanA<<<SCAN_B, 256, 0, stream>>>(rowst, dinv, bsum, N);
    k_scanB<<<SCAN_B, 256, 0, stream>>>(rowst, bsum, N);
    k_hs<float><<<(N + 63) / 64, 256, 0, stream>>>(x, Wg, dinv, hs, N);
    for (int p = 0; p < NP; ++p) {
      int lo = p * span, hi = min(lo + span, N);
      if (lo >= hi) break;
      k_fill<int><<<(E + 255) / 256, 256, 0, stream>>>(edge, E, flag, rowst,
                                                       csr, lo, hi);
    }
    int gwaves = (N + 3) / 4;
    k_gather4<float, float, int><<<(gwaves * 64 + 255) / 256, 256, 0, stream>>>(
        csr, rowst, hs, dinv, bg, gout, N);
    k_lstm<float><<<(N + 255) / 256, 1024, 0, stream>>>(gout, wimg, fcb,
                                                        (float*)d_out, N);
  } else {
    // ---- path C: scatter fallback ----
    float* gout = (float*)(ws + take((size_t)N * 128));
    __hip_bfloat16* hs = (__hip_bfloat16*)(ws + take((size_t)N * 64));
    hipMemsetAsync(gout, 0, (size_t)N * 128, stream);
    k_detect<<<1, 1, 0, stream>>>(edge, E, flag);
    k_count<<<(E + 255) / 256, 256, 0, stream>>>(edge, E, flag, rowst);
    k_dinv<<<(N + 255) / 256, 256, 0, stream>>>(rowst, dinv, N);
    k_hs<__hip_bfloat16><<<(N + 63) / 64, 256, 0, stream>>>(x, Wg, dinv, hs, N);
    int sc_blocks = (int)(((long long)E * 8 + 255) / 256);
    k_scatter<__hip_bfloat16><<<sc_blocks, 256, 0, stream>>>(edge, E, flag, hs, gout);
    k_finish<__hip_bfloat16><<<(N * 32 + 255) / 256, 256, 0, stream>>>(
        hs, dinv, bg, gout, N);
    k_lstm<float><<<(N + 255) / 256, 1024, 0, stream>>>(gout, wimg, fcb,
                                                        (float*)d_out, N);
  }
}

// Round 16
// 323.034 us; speedup vs baseline: 1.0147x; 1.0132x over previous
//
#include <hip/hip_runtime.h>
#include <hip/hip_bf16.h>

typedef __attribute__((ext_vector_type(8))) short short8;
typedef __attribute__((ext_vector_type(4))) float f32x4;

#define L2E 1.442695041f
#define SCAN_B 256

__device__ __forceinline__ short f2bf(float f) {
  union { __hip_bfloat16 b; short s; } u;
  u.b = __float2bfloat16(f);
  return u.s;
}
__device__ __forceinline__ float b2f(short s) {
  unsigned u = ((unsigned)(unsigned short)s) << 16;
  return __uint_as_float(u);
}

// ---- f32/bf16 storage accessors ----
__device__ __forceinline__ float ldh(const float* p, size_t i) { return p[i]; }
__device__ __forceinline__ float ldh(const __hip_bfloat16* p, size_t i) {
  return __bfloat162float(p[i]);
}
__device__ __forceinline__ void sth(float* p, size_t i, float v) { p[i] = v; }
__device__ __forceinline__ void sth(__hip_bfloat16* p, size_t i, float v) {
  p[i] = __float2bfloat16(v);
}

__device__ __forceinline__ short8 load_gfrag(const float* g, size_t base) {
  const float4* gp = (const float4*)(g + base);
  float4 a = gp[0], b = gp[1];
  short8 t;
  t[0]=f2bf(a.x); t[1]=f2bf(a.y); t[2]=f2bf(a.z); t[3]=f2bf(a.w);
  t[4]=f2bf(b.x); t[5]=f2bf(b.y); t[6]=f2bf(b.z); t[7]=f2bf(b.w);
  return t;
}
__device__ __forceinline__ short8 load_gfrag(const __hip_bfloat16* g, size_t base) {
  return *(const short8*)(g + base);
}

// ---------------- weight image layout (bytes) ----------------
#define OFF_WIH0 0        // bf16 [208][32], swz (row&3)<<3, exp2-prescaled
#define OFF_WHH0 13312    // bf16 [208][64], swz (row&7)<<3, exp2-prescaled
#define OFF_WIH1 39936
#define OFF_WHH1 66560
#define OFF_B0   93184    // f32 [208], exp2-prescaled
#define OFF_B1   94016
#define OFF_FCW  94848    // f32 [64] (raw, zero-padded 50..63)
#define IMG_BYTES 95104

// ================= edge dtype autodetect (A/C paths) =================
__global__ void k_detect(const int* __restrict__ ei, int E, int* __restrict__ flag) {
  if (threadIdx.x == 0 && blockIdx.x == 0) {
    int odd_nz = 0, even_nz = 0;
    int m = min(128, E);
    for (int i = 0; i < m; ++i) {
      odd_nz |= (ei[2 * i + 1] != 0);
      even_nz |= (ei[2 * i] != 0);
    }
    *flag = (even_nz && !odd_nz) ? 1 : 0;
  }
}

// ================= GCN =================

__global__ void k_count(const int* __restrict__ ei, int E,
                        const int* __restrict__ flag, int* __restrict__ cnt) {
  int e = blockIdx.x * blockDim.x + threadIdx.x;
  if (e < E) {
    int d = (*flag) ? ei[2 * (E + e)] : ei[E + e];
    atomicAdd(&cnt[d], 1);
  }
}

// read edges once: block-local dtype detect + packed emit + count atomics
__global__ void k_convert(const int* __restrict__ ei, int E,
                          unsigned int* __restrict__ ed, int* __restrict__ cnt) {
  __shared__ int sflag;
  if (threadIdx.x == 0) {
    int odd_nz = 0, even_nz = 0;
    int m = min(128, E);
    for (int i = 0; i < m; ++i) {
      odd_nz |= (ei[2 * i + 1] != 0);
      even_nz |= (ei[2 * i] != 0);
    }
    sflag = (even_nz && !odd_nz) ? 1 : 0;
  }
  __syncthreads();
  int is64 = sflag;
  int e = blockIdx.x * blockDim.x + threadIdx.x;
  if (e < E) {
    int s = is64 ? ei[2 * e] : ei[e];
    int d = is64 ? ei[2 * (E + e)] : ei[E + e];
    ed[e] = (unsigned int)s | ((unsigned int)d << 16);
    atomicAdd(&cnt[d], 1);
  }
}

__global__ void k_dinv(const int* __restrict__ cnt, float* __restrict__ dinv, int N) {
  int i = blockIdx.x * blockDim.x + threadIdx.x;
  if (i < N) dinv[i] = rsqrtf((float)cnt[i] + 1.0f);
}

// ---- grid-parallel scan, stage A: per-block sums (+dinv emission) ----
__global__ __launch_bounds__(256) void k_scanA(const int* __restrict__ cnt,
                                               float* __restrict__ dinv,
                                               int* __restrict__ bsum, int N) {
  __shared__ int red[256];
  int b = blockIdx.x, t = threadIdx.x;
  int chunk = (N + SCAN_B - 1) / SCAN_B;
  int lo = b * chunk, hi = min(lo + chunk, N);
  int s = 0;
  for (int i = lo + t; i < hi; i += 256) {
    int c = cnt[i];
    dinv[i] = rsqrtf((float)c + 1.0f);
    s += c;
  }
  red[t] = s;
  __syncthreads();
  for (int o = 128; o > 0; o >>= 1) {
    if (t < o) red[t] += red[t + o];
    __syncthreads();
  }
  if (t == 0) bsum[b] = red[0];
}

// ---- stage B: block base from bsum-scan, then tiled in-place excl scan ----
__global__ __launch_bounds__(256) void k_scanB(int* __restrict__ a,
                                               const int* __restrict__ bsum,
                                               int N) {
  __shared__ int sh[256];
  int b = blockIdx.x, t = threadIdx.x;
  int chunk = (N + SCAN_B - 1) / SCAN_B;
  int lo = b * chunk, hi = min(lo + chunk, N);
  sh[t] = bsum[t];
  __syncthreads();
  for (int o = 1; o < 256; o <<= 1) {
    int u = (t >= o) ? sh[t - o] : 0;
    __syncthreads();
    sh[t] += u;
    __syncthreads();
  }
  int carry = (b == 0) ? 0 : sh[b - 1];
  __syncthreads();
  for (int i0 = lo; i0 < hi; i0 += 256) {
    int i = i0 + t;
    int c = (i < hi) ? a[i] : 0;
    sh[t] = c;
    __syncthreads();
    for (int o = 1; o < 256; o <<= 1) {
      int u = (t >= o) ? sh[t - o] : 0;
      __syncthreads();
      sh[t] += u;
      __syncthreads();
    }
    if (i < hi) a[i] = carry + sh[t] - c;  // exclusive
    carry += sh[255];
    __syncthreads();
  }
}

// packed fill pass: dst-range window keeps csr writes L2-coalesced
__global__ void k_fill_p(const unsigned int* __restrict__ ed, int E,
                         int* __restrict__ rowst,
                         unsigned short* __restrict__ csr, int lo, int hi) {
  int e = blockIdx.x * blockDim.x + threadIdx.x;
  if (e < E) {
    unsigned int v = ed[e];
    int d = (int)(v >> 16);
    if (d >= lo && d < hi) {
      int p = atomicAdd(&rowst[d], 1);
      csr[p] = (unsigned short)(v & 0xFFFFu);
    }
  }
}

// legacy fill (path A)
template <typename CT>
__global__ void k_fill(const int* __restrict__ ei, int E,
                       const int* __restrict__ flag,
                       int* __restrict__ rowst, CT* __restrict__ csr,
                       int lo, int hi) {
  int e = blockIdx.x * blockDim.x + threadIdx.x;
  if (e < E) {
    int is64 = *flag;
    int d = is64 ? ei[2 * (E + e)] : ei[E + e];
    if (d >= lo && d < hi) {
      int s = is64 ? ei[2 * e] : ei[e];
      int p = atomicAdd(&rowst[d], 1);
      csr[p] = (CT)s;
    }
  }
}

// hs[n][g] = (x[n] @ W)[g] * dinv[n]
template <typename HT>
__global__ __launch_bounds__(256) void k_hs(const float* __restrict__ x,
                                            const float* __restrict__ Wg,
                                            const float* __restrict__ dinv,
                                            HT* __restrict__ hs, int N) {
  __shared__ __align__(16) float xt[64][132];
  __shared__ __align__(16) float Wl[128][32];
  int tid = threadIdx.x;
  int nb = blockIdx.x * 64;
  for (int i = tid; i < 4096; i += 256) Wl[i >> 5][i & 31] = Wg[i];
  const float4* xv = (const float4*)x;
  for (int i = tid; i < 2048; i += 256) {
    int r = i >> 5, c = i & 31;
    float4 v = make_float4(0.f, 0.f, 0.f, 0.f);
    if (nb + r < N) v = xv[(size_t)(nb + r) * 32 + c];
    *(float4*)&xt[r][c * 4] = v;
  }
  __syncthreads();
  int nl = tid >> 2, gq = (tid & 3) * 8;
  float a[8];
#pragma unroll
  for (int j = 0; j < 8; ++j) a[j] = 0.f;
  for (int k = 0; k < 128; ++k) {
    float xk = xt[nl][k];
#pragma unroll
    for (int j = 0; j < 8; ++j) a[j] += xk * Wl[k][gq + j];
  }
  int n = nb + nl;
  if (n < N) {
    float d = dinv[n];
#pragma unroll
    for (int j = 0; j < 8; ++j) sth(hs, (size_t)n * 32 + gq + j, a[j] * d);
  }
}

// 4 nodes per wave; batched rowst window load + 4 prefetched idx loads
template <typename HT, typename GT, typename CT>
__global__ void k_gather4(const CT* __restrict__ csr, const int* __restrict__ rowst,
                          const HT* __restrict__ hs, const float* __restrict__ dinv,
                          const float* __restrict__ bg, GT* __restrict__ gout,
                          int N) {
  long long gtid = (long long)blockIdx.x * blockDim.x + threadIdx.x;
  int wave = (int)(gtid >> 6);
  int n0 = wave * 4;
  if (n0 >= N) return;
  int l = threadIdx.x & 63;
  int gf = l & 31, j = l >> 5;
  // lanes 0..4 hold rowst[n0-1 .. n0+3] (0 when OOB)
  int rr = 0;
  int ri = n0 - 1 + l;
  if (l <= 4 && ri >= 0 && ri < N) rr = rowst[ri];
  int st[4], en[4], idx[4], deg[4];
#pragma unroll
  for (int q = 0; q < 4; ++q) {
    st[q] = __shfl(rr, q);
    en[q] = __shfl(rr, q + 1);
    deg[q] = en[q] - st[q];
  }
#pragma unroll
  for (int q = 0; q < 4; ++q)
    idx[q] = (n0 + q < N && l < deg[q]) ? (int)csr[st[q] + l] : 0;
  float bgv = bg[gf];
#pragma unroll
  for (int q = 0; q < 4; ++q) {
    int w = n0 + q;
    if (w >= N) break;
    float acc = 0.f;
    int dm = min(deg[q], 64);
#pragma unroll 1
    for (int base = 0; base < 64; base += 16) {
      if (base >= dm) break;
#pragma unroll
      for (int i = 0; i < 8; ++i) {
        int e = base + 2 * i + j;
        int src = __shfl(idx[q], e);
        float v = ldh(hs, (size_t)src * 32 + gf);
        acc += (e < dm) ? v : 0.f;
      }
    }
    for (int k2 = st[q] + 64 + j; k2 < en[q]; k2 += 2)
      acc += ldh(hs, (size_t)csr[k2] * 32 + gf);
    acc += __shfl_xor(acc, 32);
    if (j == 0) {
      float v = (acc + ldh(hs, (size_t)w * 32 + gf)) * dinv[w] + bgv;
      sth(gout, (size_t)w * 32 + gf, v);
    }
  }
}

// ---- scatter fallback ----
template <typename HT>
__global__ void k_scatter(const int* __restrict__ ei, int E,
                          const int* __restrict__ flag,
                          const HT* __restrict__ hs, float* __restrict__ gout) {
  long long gid = (long long)blockIdx.x * blockDim.x + threadIdx.x;
  int e = (int)(gid >> 3), part = (int)(gid & 7);
  if (e >= E) return;
  int is64 = *flag;
  int s = is64 ? ei[2 * e] : ei[e];
  int d = is64 ? ei[2 * (E + e)] : ei[E + e];
  int b = part * 4;
  float* gp = gout + (size_t)d * 32 + b;
  size_t hp = (size_t)s * 32 + b;
  atomicAdd(gp + 0, ldh(hs, hp + 0));
  atomicAdd(gp + 1, ldh(hs, hp + 1));
  atomicAdd(gp + 2, ldh(hs, hp + 2));
  atomicAdd(gp + 3, ldh(hs, hp + 3));
}
template <typename HT>
__global__ void k_finish(const HT* __restrict__ hs, const float* __restrict__ dinv,
                         const float* __restrict__ bg, float* __restrict__ gout,
                         int N) {
  int gid = blockIdx.x * blockDim.x + threadIdx.x;
  if (gid < N * 32) {
    int n = gid >> 5, g = gid & 31;
    gout[gid] = (gout[gid] + ldh(hs, (size_t)gid)) * dinv[n] + bg[g];
  }
}

// ============ weight image prep (exp2-prescaled) + rowst zeroing ============
__global__ void k_prep(const float* __restrict__ wih0, const float* __restrict__ whh0,
                       const float* __restrict__ wih1, const float* __restrict__ whh1,
                       const float* __restrict__ bih0, const float* __restrict__ bhh0,
                       const float* __restrict__ bih1, const float* __restrict__ bhh1,
                       const float* __restrict__ fcw, unsigned char* __restrict__ img,
                       int* __restrict__ rowst, int N) {
  int gid = blockIdx.x * blockDim.x + threadIdx.x;
  int nthr = gridDim.x * blockDim.x;
  for (int i = gid; i < N; i += nthr) rowst[i] = 0;
  {
    short* W = (short*)(img + OFF_WIH0);
    for (int i = gid; i < 208 * 32; i += nthr) {
      int row = i >> 5, k = i & 31, u = row >> 2, q = row & 3;
      float sc = (q == 2) ? 2.0f * L2E : -L2E;
      float v = (u < 50) ? wih0[(q * 50 + u) * 32 + k] * sc : 0.0f;
      W[row * 32 + (k ^ ((row & 3) << 3))] = f2bf(v);
    }
  }
  {
    short* W = (short*)(img + OFF_WHH0);
    for (int i = gid; i < 208 * 64; i += nthr) {
      int row = i >> 6, k = i & 63, u = row >> 2, q = row & 3;
      float sc = (q == 2) ? 2.0f * L2E : -L2E;
      float v = (u < 50 && k < 50) ? whh0[(q * 50 + u) * 50 + k] * sc : 0.0f;
      W[row * 64 + (k ^ ((row & 7) << 3))] = f2bf(v);
    }
  }
  {
    short* W = (short*)(img + OFF_WIH1);
    for (int i = gid; i < 208 * 64; i += nthr) {
      int row = i >> 6, k = i & 63, u = row >> 2, q = row & 3;
      float sc = (q == 2) ? 2.0f * L2E : -L2E;
      float v = (u < 50 && k < 50) ? wih1[(q * 50 + u) * 50 + k] * sc : 0.0f;
      W[row * 64 + (k ^ ((row & 7) << 3))] = f2bf(v);
    }
  }
  {
    short* W = (short*)(img + OFF_WHH1);
    for (int i = gid; i < 208 * 64; i += nthr) {
      int row = i >> 6, k = i & 63, u = row >> 2, q = row & 3;
      float sc = (q == 2) ? 2.0f * L2E : -L2E;
      float v = (u < 50 && k < 50) ? whh1[(q * 50 + u) * 50 + k] * sc : 0.0f;
      W[row * 64 + (k ^ ((row & 7) << 3))] = f2bf(v);
    }
  }
  {
    float* B = (float*)(img + OFF_B0);
    for (int i = gid; i < 208; i += nthr) {
      int u = i >> 2, q = i & 3;
      float sc = (q == 2) ? 2.0f * L2E : -L2E;
      B[i] = (u < 50) ? (bih0[q * 50 + u] + bhh0[q * 50 + u]) * sc : 0.0f;
    }
  }
  {
    float* B = (float*)(img + OFF_B1);
    for (int i = gid; i < 208; i += nthr) {
      int u = i >> 2, q = i & 3;
      float sc = (q == 2) ? 2.0f * L2E : -L2E;
      B[i] = (u < 50) ? (bih1[q * 50 + u] + bhh1[q * 50 + u]) * sc : 0.0f;
    }
  }
  {
    float* F = (float*)(img + OFF_FCW);
    for (int i = gid; i < 64; i += nthr) F[i] = (i < 50) ? fcw[i] : 0.0f;
  }
}

// exp2-domain gates, rcp-paired: 5 exp2 + 3 rcp
__device__ __forceinline__ float gate_update(const f32x4& acc, float& cp) {
  float ei = __builtin_amdgcn_exp2f(acc[0]);
  float ef = __builtin_amdgcn_exp2f(acc[1]);
  float eo = __builtin_amdgcn_exp2f(acc[3]);
  float eg = __builtin_amdgcn_exp2f(fminf(acc[2], 80.0f));
  float a = 1.0f + ei, b = 1.0f + ef;
  float rif = __builtin_amdgcn_rcpf(a * b);
  float iv = rif * b, fv = rif * a;
  float o1 = 1.0f + eo, g1 = eg + 1.0f;
  float rog = __builtin_amdgcn_rcpf(o1 * g1);
  float ov = rog * g1;
  float gv = (eg - 1.0f) * (rog * o1);
  float c = fv * cp + iv * gv;
  cp = c;
  float Ec = __builtin_amdgcn_exp2f(c * (2.0f * L2E));
  float th = (Ec - 1.0f) * __builtin_amdgcn_rcpf(Ec + 1.0f);
  return ov * th;
}

// ===== fused 2-layer MFMA LSTM (r13-proven: 8 waves x 32 nodes, VGPR 128) ====
template <typename GT>
__global__ __launch_bounds__(512, 2) void k_lstm(const GT* __restrict__ gout,
    const unsigned char* __restrict__ img, const float* __restrict__ fcb_p,
    float* __restrict__ out, int N) {
  __shared__ __align__(16) unsigned char smem[160640];  // 95104 img + 8*8192
  const int tid = threadIdx.x;
  {
    const uint4* s = (const uint4*)img;
    uint4* d = (uint4*)smem;
    for (int i = tid; i < IMG_BYTES / 16; i += 512) d[i] = s[i];
  }
  __syncthreads();
  const int lane = tid & 63, wid = tid >> 6;
  const int l15 = lane & 15, l4 = lane >> 4;
  const int swz7 = (l15 & 7) << 3, swz3 = (l15 & 3) << 3;
  const int node0 = blockIdx.x * 256 + wid * 32;

  const short* WIH0 = (const short*)(smem + OFF_WIH0);
  const short* WHH0 = (const short*)(smem + OFF_WHH0);
  const short* WIH1 = (const short*)(smem + OFF_WIH1);
  const short* WHH1 = (const short*)(smem + OFF_WHH1);
  const float* B0   = (const float*)(smem + OFF_B0);
  const float* B1   = (const float*)(smem + OFF_B1);
  const float* FCW  = (const float*)(smem + OFF_FCW);
  short* h0st = (short*)(smem + IMG_BYTES + wid * 8192);
  short* h1st = h0st + 2048;

  {
    uint4 z; z.x = z.y = z.z = z.w = 0u;
    uint4* p = (uint4*)h0st;
    for (int i = lane; i < 512; i += 64) p[i] = z;
  }

  f32x4 p0r[13][2];
  {
    short8 gfrag[2];
#pragma unroll
    for (int v = 0; v < 2; ++v) {
      int node = node0 + v * 16 + l15;
      short8 t = {0, 0, 0, 0, 0, 0, 0, 0};
      if (node < N) t = load_gfrag(gout, (size_t)node * 32 + l4 * 8);
      gfrag[v] = t;
    }
#pragma unroll
    for (int t = 0; t < 13; ++t) {
      short8 w = *(const short8*)(WIH0 + (16 * t + l15) * 32 + ((l4 * 8) ^ swz3));
      f32x4 bv = *(const f32x4*)(B0 + t * 16 + l4 * 4);
#pragma unroll
      for (int v = 0; v < 2; ++v)
        p0r[t][v] = __builtin_amdgcn_mfma_f32_16x16x32_bf16(w, gfrag[v], bv, 0, 0, 0);
    }
  }

  float c0[13][2], c1[13][2];
#pragma unroll
  for (int t = 0; t < 13; ++t) { c0[t][0]=0.f; c0[t][1]=0.f; c1[t][0]=0.f; c1[t][1]=0.f; }

#pragma unroll 1
  for (int s = 0; s < 10; ++s) {
    short8 h0f[2][2], h1f[2][2];
#pragma unroll
    for (int c = 0; c < 2; ++c)
#pragma unroll
      for (int v = 0; v < 2; ++v) {
        int nl = v * 16 + l15;
        h0f[c][v] = *(const short8*)(h0st + nl * 64 + ((c * 32 + l4 * 8) ^ swz7));
        h1f[c][v] = *(const short8*)(h1st + nl * 64 + ((c * 32 + l4 * 8) ^ swz7));
      }
#pragma unroll
    for (int t = 0; t < 13; ++t) {
      int arow = (16 * t + l15);
      short8 ah0 = *(const short8*)(WHH0 + arow * 64 + ((l4 * 8) ^ swz7));
      short8 ah1 = *(const short8*)(WHH0 + arow * 64 + ((32 + l4 * 8) ^ swz7));
#pragma unroll
      for (int v = 0; v < 2; ++v) {
        f32x4 acc = p0r[t][v];
        acc = __builtin_amdgcn_mfma_f32_16x16x32_bf16(ah0, h0f[0][v], acc, 0, 0, 0);
        acc = __builtin_amdgcn_mfma_f32_16x16x32_bf16(ah1, h0f[1][v], acc, 0, 0, 0);
        float h = gate_update(acc, c0[t][v]);
        h0st[(v * 16 + l15) * 64 + ((4 * t + l4) ^ swz7)] = f2bf(h);
      }
    }
    short8 h0nf[2][2];
#pragma unroll
    for (int c = 0; c < 2; ++c)
#pragma unroll
      for (int v = 0; v < 2; ++v) {
        int nl = v * 16 + l15;
        h0nf[c][v] = *(const short8*)(h0st + nl * 64 + ((c * 32 + l4 * 8) ^ swz7));
      }
#pragma unroll
    for (int t = 0; t < 13; ++t) {
      f32x4 bv = *(const f32x4*)(B1 + t * 16 + l4 * 4);
      int arow = (16 * t + l15);
      short8 ai0 = *(const short8*)(WIH1 + arow * 64 + ((l4 * 8) ^ swz7));
      short8 ai1 = *(const short8*)(WIH1 + arow * 64 + ((32 + l4 * 8) ^ swz7));
      short8 ah0 = *(const short8*)(WHH1 + arow * 64 + ((l4 * 8) ^ swz7));
      short8 ah1 = *(const short8*)(WHH1 + arow * 64 + ((32 + l4 * 8) ^ swz7));
#pragma unroll
      for (int v = 0; v < 2; ++v) {
        f32x4 acc = bv;
        acc = __builtin_amdgcn_mfma_f32_16x16x32_bf16(ai0, h0nf[0][v], acc, 0, 0, 0);
        acc = __builtin_amdgcn_mfma_f32_16x16x32_bf16(ai1, h0nf[1][v], acc, 0, 0, 0);
        acc = __builtin_amdgcn_mfma_f32_16x16x32_bf16(ah0, h1f[0][v], acc, 0, 0, 0);
        acc = __builtin_amdgcn_mfma_f32_16x16x32_bf16(ah1, h1f[1][v], acc, 0, 0, 0);
        float h = gate_update(acc, c1[t][v]);
        h1st[(v * 16 + l15) * 64 + ((4 * t + l4) ^ swz7)] = f2bf(h);
      }
    }
  }
  float fcb = fcb_p[0];
#pragma unroll
  for (int v = 0; v < 2; ++v) {
    int nl = v * 16 + l15;
    float facc = 0.f;
#pragma unroll
    for (int c = 0; c < 2; ++c) {
      short8 f = *(const short8*)(h1st + nl * 64 + ((c * 32 + l4 * 8) ^ swz7));
#pragma unroll
      for (int j = 0; j < 8; ++j)
        facc += b2f(f[j]) * FCW[c * 32 + l4 * 8 + j];
    }
    facc += __shfl_xor(facc, 16);
    facc += __shfl_xor(facc, 32);
    int node = node0 + v * 16 + l15;
    if (l4 == 0 && node < N) out[node] = facc + fcb;
  }
}

// ================= host launcher =================
extern "C" void kernel_launch(void* const* d_in, const int* in_sizes, int n_in,
                              void* d_out, int out_size, void* d_ws, size_t ws_size,
                              hipStream_t stream) {
  const float* x    = (const float*)d_in[0];
  const float* Wg   = (const float*)d_in[1];
  const float* bg   = (const float*)d_in[2];
  const float* wih0 = (const float*)d_in[3];
  const float* whh0 = (const float*)d_in[4];
  const float* bih0 = (const float*)d_in[5];
  const float* bhh0 = (const float*)d_in[6];
  const float* wih1 = (const float*)d_in[7];
  const float* whh1 = (const float*)d_in[8];
  const float* bih1 = (const float*)d_in[9];
  const float* bhh1 = (const float*)d_in[10];
  const float* fcw  = (const float*)d_in[11];
  const float* fcb  = (const float*)d_in[12];
  const int*   edge = (const int*)d_in[13];
  int N = in_sizes[0] / 128;
  int E = in_sizes[13] / 2;

  char* ws = (char*)d_ws;
  size_t off = 0;
  auto take = [&](size_t b) {
    size_t o = off;
    off = (off + b + 255) & ~(size_t)255;
    return o;
  };
  int*   rowst = (int*)(ws + take((size_t)N * 4));
  float* dinv  = (float*)(ws + take((size_t)N * 4));
  int*   flag  = (int*)(ws + take(256));
  unsigned char* wimg = (unsigned char*)(ws + take(IMG_BYTES));
  size_t base = off;

  const int NP = 4;
  int span = (N + NP - 1) / NP;
  bool canU16 = (N <= 65535) && (E <= 100000000);

  size_t csr_b  = ((size_t)E * 2 + 255) & ~(size_t)255;
  size_t hsb    = ((size_t)N * 64 + 255) & ~(size_t)255;
  size_t reg2_b = (size_t)E * 4 > 2 * hsb ? (size_t)E * 4 : 2 * hsb;
  size_t needP  = base + csr_b + reg2_b;
  size_t needA = base + (((size_t)N * 128 + 255) & ~(size_t)255)
               + (((size_t)E * 4 + 255) & ~(size_t)255)
               + ((size_t)N * 128);

  // prep also zeros rowst (must precede count/convert)
  k_prep<<<52, 256, 0, stream>>>(wih0, whh0, wih1, whh1, bih0, bhh0, bih1, bhh1,
                                 fcw, wimg, rowst, N);

  if (canU16 && ws_size >= needP) {
    // ---- path P: packed edges, u16 csr, bf16 hs/gout (split kernels) ----
    unsigned short* csr = (unsigned short*)(ws + take(csr_b));
    char* reg2 = ws + take(reg2_b);
    unsigned int*   ed   = (unsigned int*)reg2;
    __hip_bfloat16* hs   = (__hip_bfloat16*)reg2;
    __hip_bfloat16* gout = (__hip_bfloat16*)(reg2 + hsb);
    int* bsum = (int*)csr;  // transient alias (scan before fill)

    k_convert<<<(E + 255) / 256, 256, 0, stream>>>(edge, E, ed, rowst);
    k_scanA<<<SCAN_B, 256, 0, stream>>>(rowst, dinv, bsum, N);
    k_scanB<<<SCAN_B, 256, 0, stream>>>(rowst, bsum, N);
    for (int p = 0; p < NP; ++p) {
      int lo = p * span, hi = min(lo + span, N);
      if (lo >= hi) break;
      k_fill_p<<<(E + 255) / 256, 256, 0, stream>>>(ed, E, rowst, csr, lo, hi);
    }
    k_hs<__hip_bfloat16><<<(N + 63) / 64, 256, 0, stream>>>(x, Wg, dinv, hs, N);
    int gwaves = (N + 3) / 4;
    k_gather4<__hip_bfloat16, __hip_bfloat16, unsigned short>
        <<<(gwaves * 64 + 255) / 256, 256, 0, stream>>>(csr, rowst, hs, dinv,
                                                        bg, gout, N);
    k_lstm<__hip_bfloat16><<<(N + 255) / 256, 512, 0, stream>>>(gout, wimg, fcb,
                                                                (float*)d_out, N);
  } else if (ws_size >= needA) {
    // ---- path A: f32 everything, u32 csr ----
    float* gout = (float*)(ws + take((size_t)N * 128));
    int*   csr  = (int*)(ws + take((size_t)E * 4));
    float* hs   = (float*)(ws + take((size_t)N * 128));
    int*   bsum = (int*)csr;
    k_detect<<<1, 1, 0, stream>>>(edge, E, flag);
    k_count<<<(E + 255) / 256, 256, 0, stream>>>(edge, E, flag, rowst);
    k_scanA<<<SCAN_B, 256, 0, stream>>>(rowst, dinv, bsum, N);
    k_scanB<<<SCAN_B, 256, 0, stream>>>(rowst, bsum, N);
    k_hs<float><<<(N + 63) / 64, 256, 0, stream>>>(x, Wg, dinv, hs, N);
    for (int p = 0; p < NP; ++p) {
      int lo = p * span, hi = min(lo + span, N);
      if (lo >= hi) break;
      k_fill<int><<<(E + 255) / 256, 256, 0, stream>>>(edge, E, flag, rowst,
                                                       csr, lo, hi);
    }
    int gwaves = (N + 3) / 4;
    k_gather4<float, float, int><<<(gwaves * 64 + 255) / 256, 256, 0, stream>>>(
        csr, rowst, hs, dinv, bg, gout, N);
    k_lstm<float><<<(N + 255) / 256, 512, 0, stream>>>(gout, wimg, fcb,
                                                       (float*)d_out, N);
  } else {
    // ---- path C: scatter fallback ----
    float* gout = (float*)(ws + take((size_t)N * 128));
    __hip_bfloat16* hs = (__hip_bfloat16*)(ws + take((size_t)N * 64));
    hipMemsetAsync(gout, 0, (size_t)N * 128, stream);
    k_detect<<<1, 1, 0, stream>>>(edge, E, flag);
    k_count<<<(E + 255) / 256, 256, 0, stream>>>(edge, E, flag, rowst);
    k_dinv<<<(N + 255) / 256, 256, 0, stream>>>(rowst, dinv, N);
    k_hs<__hip_bfloat16><<<(N + 63) / 64, 256, 0, stream>>>(x, Wg, dinv, hs, N);
    int sc_blocks = (int)(((long long)E * 8 + 255) / 256);
    k_scatter<__hip_bfloat16><<<sc_blocks, 256, 0, stream>>>(edge, E, flag, hs, gout);
    k_finish<__hip_bfloat16><<<(N * 32 + 255) / 256, 256, 0, stream>>>(
        hs, dinv, bg, gout, N);
    k_lstm<float><<<(N + 255) / 256, 512, 0, stream>>>(gout, wimg, fcb,
                                                       (float*)d_out, N);
  }
}